// Round 4
// baseline (351.900 us; speedup 1.0000x reference)
//
#include <hip/hip_runtime.h>

#define NC 19
#define NPK 20               // packed u16-pair registers: 10 for U, 10 for I
#define EPS 1e-5f

typedef unsigned long long u64;

// Add 1 to the 6-bit field for class value encoded as s6 = 6*cls.
// Classes 0..9 -> lo (shifts 0..54), classes 10..19 -> hi. The not-selected
// half adds (0 << garbage) == 0, so no branch, no carry-chain coupling.
__device__ __forceinline__ void acc6(u64& lo, u64& hi, unsigned s6) {
    unsigned islo = (s6 < 60u) ? 1u : 0u;
    lo += (u64)islo << (s6 & 63u);
    hi += (u64)(islo ^ 1u) << ((s6 - 60u) & 63u);
}

__device__ __forceinline__ void elem(int t, int p,
                                     u64& tlo, u64& thi,
                                     u64& plo, u64& phi,
                                     u64& qlo, u64& qhi) {
    unsigned t6 = (unsigned)t * 6u;
    unsigned p6 = (unsigned)p * 6u;
    unsigned q6 = (t == p) ? t6 : 114u;   // sentinel -> hi field 9 (junk)
    acc6(tlo, thi, t6);
    acc6(plo, phi, p6);
    acc6(qlo, qhi, q6);
}

// Extract 6-bit field of class c (compile-time c in unrolled loops).
__device__ __forceinline__ unsigned fld(u64 lo, u64 hi, int c) {
    return (c < 10) ? ((unsigned)(lo >> (6 * c)) & 63u)
                    : ((unsigned)(hi >> (6 * (c - 10))) & 63u);
}

// Unpack phase accumulators into the u16-packed running counters.
__device__ __forceinline__ void unpack_phase(
    u64 tlo, u64 thi, u64 plo, u64 phi, u64 qlo, u64 qhi,
    unsigned* __restrict__ pU, unsigned* __restrict__ pI)
{
    #pragma unroll
    for (int j = 0; j < 10; ++j) {
        const int c0 = 2 * j, c1 = 2 * j + 1;
        unsigned ulo = fld(tlo, thi, c0) + fld(plo, phi, c0);
        unsigned uhi = (c1 < NC) ? (fld(tlo, thi, c1) + fld(plo, phi, c1)) : 0u;
        pU[j] += ulo | (uhi << 16);
        unsigned ilo = fld(qlo, qhi, c0);
        unsigned ihi = (c1 < NC) ? fld(qlo, qhi, c1) : 0u;
        pI[j] += ilo | (ihi << 16);
    }
}

// __launch_bounds__(256, 4): 4 waves/SIMD -> 128-VGPR budget. The live set
// (~106 VGPRs: 16 batched int4 loads + 12 accumulator + 20 counter regs)
// must NOT spill to scratch -- that was R2/R3's hidden stall (VGPR=36/40).
__global__ __launch_bounds__(256, 4) void dice_main(
    const int4* __restrict__ yp, const int4* __restrict__ yt,
    unsigned* __restrict__ gU, unsigned* __restrict__ gI,
    unsigned* __restrict__ ticket, float* __restrict__ out, int n4)
{
    unsigned pU[10], pI[10];   // u16-packed per-thread counters (classes 2j, 2j+1)
    #pragma unroll
    for (int j = 0; j < 10; ++j) { pU[j] = 0u; pI[j] = 0u; }

    const int stride = gridDim.x * 256;
    int i = blockIdx.x * 256 + threadIdx.x;

    // Full phases: 8 int4-iterations, no guards (max 32 adds/field <= 63).
    while (i + 7 * stride < n4) {
        int4 tv[8], pv[8];
        #pragma unroll
        for (int k = 0; k < 8; ++k) {
            tv[k] = yt[i + k * stride];
            pv[k] = yp[i + k * stride];
        }
        u64 tlo = 0, thi = 0, plo = 0, phi = 0, qlo = 0, qhi = 0;
        #pragma unroll
        for (int k = 0; k < 8; ++k) {
            elem(tv[k].x, pv[k].x, tlo, thi, plo, phi, qlo, qhi);
            elem(tv[k].y, pv[k].y, tlo, thi, plo, phi, qlo, qhi);
            elem(tv[k].z, pv[k].z, tlo, thi, plo, phi, qlo, qhi);
            elem(tv[k].w, pv[k].w, tlo, thi, plo, phi, qlo, qhi);
        }
        unpack_phase(tlo, thi, plo, phi, qlo, qhi, pU, pI);
        i += 8 * stride;
    }

    // Tail: up to 7 guarded iterations (never taken for n4 = 16*stride).
    if (i < n4) {
        u64 tlo = 0, thi = 0, plo = 0, phi = 0, qlo = 0, qhi = 0;
        do {
            int4 tv = yt[i];
            int4 pv = yp[i];
            elem(tv.x, pv.x, tlo, thi, plo, phi, qlo, qhi);
            elem(tv.y, pv.y, tlo, thi, plo, phi, qlo, qhi);
            elem(tv.z, pv.z, tlo, thi, plo, phi, qlo, qhi);
            elem(tv.w, pv.w, tlo, thi, plo, phi, qlo, qhi);
            i += stride;
        } while (i < n4);
        unpack_phase(tlo, thi, plo, phi, qlo, qhi, pU, pI);
    }

    // ---- epilogue (verified R2/R3): butterfly on 20 packed u32s, LDS merge,
    //      global atomics, last-block fused finalization ----
    unsigned P[NPK];
    #pragma unroll
    for (int j = 0; j < 10; ++j) { P[j] = pU[j]; P[10 + j] = pI[j]; }

    #pragma unroll
    for (int j = 0; j < NPK; ++j) {
        #pragma unroll
        for (int off = 1; off < 64; off <<= 1)
            P[j] += __shfl_xor(P[j], off, 64);
    }

    __shared__ unsigned ldsP[4 * NPK];
    __shared__ unsigned s_old;
    const int lane = threadIdx.x & 63;
    const int wv   = threadIdx.x >> 6;
    if (lane == 0) {
        #pragma unroll
        for (int j = 0; j < NPK; ++j) ldsP[wv * NPK + j] = P[j];
    }
    __syncthreads();

    if (threadIdx.x < NPK) {
        unsigned lo = 0, hi = 0;
        #pragma unroll
        for (int w = 0; w < 4; ++w) {
            unsigned v = ldsP[w * NPK + threadIdx.x];
            lo += v & 0xffffu;
            hi += v >> 16;
        }
        const int j = threadIdx.x;
        unsigned* base = (j < 10) ? gU : gI;
        const int c0 = (j < 10) ? 2 * j : 2 * (j - 10);
        atomicAdd(&base[c0], lo);
        if (c0 + 1 < NC) atomicAdd(&base[c0 + 1], hi);
    }

    __threadfence();
    __syncthreads();
    if (threadIdx.x == 0)
        s_old = __hip_atomic_fetch_add(ticket, 1u, __ATOMIC_ACQ_REL, __HIP_MEMORY_SCOPE_AGENT);
    __syncthreads();
    if (s_old == gridDim.x - 1 && threadIdx.x < 64) {
        float dice = 0.0f;
        if (lane < NC) {
            unsigned Uv = __hip_atomic_load(&gU[lane], __ATOMIC_RELAXED, __HIP_MEMORY_SCOPE_AGENT);
            unsigned Iv = __hip_atomic_load(&gI[lane], __ATOMIC_RELAXED, __HIP_MEMORY_SCOPE_AGENT);
            float I = (float)Iv;
            float U = (float)Uv;          // U = count_y + count_p; union = U - I
            dice = (2.0f * I + EPS) / ((U - I) + EPS);
        }
        #pragma unroll
        for (int off = 32; off > 0; off >>= 1)
            dice += __shfl_down(dice, off, 64);
        if (lane == 0) out[0] = 1.0f - dice * (1.0f / (float)NC);
    }
}

extern "C" void kernel_launch(void* const* d_in, const int* in_sizes, int n_in,
                              void* d_out, int out_size, void* d_ws, size_t ws_size,
                              hipStream_t stream)
{
    const int4* yp = (const int4*)d_in[0];   // y_pred, int32
    const int4* yt = (const int4*)d_in[1];   // y,      int32
    unsigned* gU     = (unsigned*)d_ws;      // 19 u32: count_y + count_p
    unsigned* gI     = gU + NC;              // 19 u32: intersection
    unsigned* ticket = gI + NC;              // 1 u32
    float* out = (float*)d_out;

    const int n  = in_sizes[0];              // 16*1024*1024
    const int n4 = n >> 2;

    hipMemsetAsync(d_ws, 0, (2 * NC + 1) * sizeof(unsigned), stream);

    // grid 1024: 4 blocks/CU, exactly 2 full phases of 8 int4 per thread.
    dice_main<<<1024, 256, 0, stream>>>(yp, yt, gU, gI, ticket, out, n4);
}